// Round 9
// baseline (187.276 us; speedup 1.0000x reference)
//
#include <hip/hip_runtime.h>
#include <float.h>
#include <math.h>

#define TOKS 16384
#define HDIM 4096
#define NEXP 64
#define BM   64          // tokens per block tile
#define BK   64          // k per chunk
#define NCH  (HDIM / BK) // 64 chunks total

typedef __attribute__((ext_vector_type(8)))  short short8v;  // 8 bf16 (A/B frag)
typedef __attribute__((ext_vector_type(16))) float f32x16;   // C/D frag

// Exact 3-way bf16 split by truncation: v = s1 + s2 + s3 + eps, eps <= 2^-24*|v|.
__device__ __forceinline__ void split3(float v, unsigned& b1, unsigned& b2, unsigned& b3) {
  unsigned xb = __float_as_uint(v);
  b1 = xb >> 16;
  float r = v - __uint_as_float(xb & 0xFFFF0000u);
  unsigned rb = __float_as_uint(r);
  b2 = rb >> 16;
  float r2 = r - __uint_as_float(rb & 0xFFFF0000u);
  b3 = __float_as_uint(r2) >> 16;
}

__device__ __forceinline__ void cvt2(float a, float b, unsigned& o1, unsigned& o2, unsigned& o3) {
  unsigned a1, a2, a3, c1, c2, c3;
  split3(a, a1, a2, a3);
  split3(b, c1, c2, c3);
  o1 = a1 | (c1 << 16); o2 = a2 | (c2 << 16); o3 = a3 | (c3 << 16);
}

// wave-wide top-8 + softmax over fin[64 tok][64 exp] (+bias), 4 waves x 16 tokens
__device__ __forceinline__ void topk_softmax(const float* fin, const float* __restrict__ bias,
                                             float* __restrict__ out, int tokBase,
                                             int lane, int wv) {
  for (int tt = 0; tt < 16; ++tt) {
    const int t = wv * 16 + tt;
    float v = fin[t * 64 + lane] + bias[lane];   // lane = expert id
    float myval = 0.f, m0 = 0.f;
    int myidx = 0;
#pragma unroll
    for (int k = 0; k < 8; ++k) {
      float bv = v;
      int   bi = lane;
#pragma unroll
      for (int off = 1; off < 64; off <<= 1) {   // argmax, min-index tiebreak
        const float ov = __shfl_xor(bv, off);
        const int   oi = __shfl_xor(bi, off);
        if (ov > bv || (ov == bv && oi < bi)) { bv = ov; bi = oi; }
      }
      if (k == 0) m0 = bv;
      if (lane == k) { myval = bv; myidx = bi; }
      if (lane == bi) v = -FLT_MAX;              // bi is wave-uniform
    }
    const float el = (lane < 8) ? expf(myval - m0) : 0.f;
    float ssum = el;
    ssum += __shfl_xor(ssum, 1);
    ssum += __shfl_xor(ssum, 2);
    ssum += __shfl_xor(ssum, 4);
    if (lane < 8) {
      const size_t tg = (size_t)(tokBase + t);
      out[tg * 8 + lane] = el / ssum;                        // weights (f32)
      out[(size_t)TOKS * 8 + tg * 8 + lane] = (float)myidx;  // indices as f32
    }
  }
}

// ---- main: block 256 thr = 4 waves, tile 64 tok x 64 exp, K-slice of HDIM ----
// grid (256 tiles, ks). R8 post-mortem: 112KB LDS dbuf -> 1 block/CU, 1 wave/
// SIMD -> everything latency-serialized at 10-19% util. Fix: single 48KB buf
// (dbuf never overlapped anyway across the barriers) + split-K grid so 3
// blocks/CU actually co-reside. Chunk pipeline byte-identical to passing R8.
__global__ __launch_bounds__(256)
void router_mfma_kernel(const float* __restrict__ x,
                        const float* __restrict__ wgt,
                        const float* __restrict__ bias,
                        float* __restrict__ out,
                        float* __restrict__ part, int ks) {
  __shared__ __align__(16) unsigned char smem[49152];
  const int tid  = threadIdx.x;
  const int lane = tid & 63;
  const int wv   = tid >> 6;
  const int kt   = blockIdx.y;
  const int tokBase = blockIdx.x * BM;
  const int cStart = (NCH * kt) / ks;
  const int cEnd   = (NCH * (kt + 1)) / ks;

  // staging: thread owns row stok (x-token and w-expert), k-seg of 16 floats
  const int stok = tid >> 2;
  const int seg  = tid & 3;
  const unsigned swz0 = (unsigned)(((seg * 2)     ^ (stok & 7)) << 4);
  const unsigned swz1 = (unsigned)(((seg * 2 + 1) ^ (stok & 7)) << 4);
  const int rowbyte_s = stok * 128;
  const float* const xrow = x   + (size_t)(tokBase + stok) * HDIM;
  const float* const wrow = wgt + (size_t)stok * HDIM;

  // compute: wave tile + frag lane mapping
  const int wm = wv >> 1, we = wv & 1;
  const int r  = lane & 31, h2 = lane >> 5;
  const int r7 = r & 7;
  const int byteA = (wm * 32 + r) * 128;
  const int byteB = (we * 32 + r) * 128;

  f32x16 acc_m0, acc_m1, acc_c;
#pragma unroll
  for (int i = 0; i < 16; ++i) { acc_m0[i] = 0.f; acc_m1[i] = 0.f; acc_c[i] = 0.f; }

  float4 nf0, nf1, nf2, nf3;   // x chunk (16 f32)
  float4 ng0, ng1, ng2, ng3;   // w chunk (16 f32)

#define GLOAD(c) do { \
    const int kb_ = (c) * BK + seg * 16; \
    nf0 = *(const float4*)(xrow + kb_);      nf1 = *(const float4*)(xrow + kb_ + 4); \
    nf2 = *(const float4*)(xrow + kb_ + 8);  nf3 = *(const float4*)(xrow + kb_ + 12); \
    ng0 = *(const float4*)(wrow + kb_);      ng1 = *(const float4*)(wrow + kb_ + 4); \
    ng2 = *(const float4*)(wrow + kb_ + 8);  ng3 = *(const float4*)(wrow + kb_ + 12); \
  } while (0)

  // split + transpose-write into LDS: 12 ds_write_b128 per thread
#define SWRITE() do { \
    unsigned char* bb_ = smem; \
    uint4 q1l, q2l, q3l, q1h, q2h, q3h; \
    cvt2(nf0.x, nf0.y, q1l.x, q2l.x, q3l.x); \
    cvt2(nf0.z, nf0.w, q1l.y, q2l.y, q3l.y); \
    cvt2(nf1.x, nf1.y, q1l.z, q2l.z, q3l.z); \
    cvt2(nf1.z, nf1.w, q1l.w, q2l.w, q3l.w); \
    cvt2(nf2.x, nf2.y, q1h.x, q2h.x, q3h.x); \
    cvt2(nf2.z, nf2.w, q1h.y, q2h.y, q3h.y); \
    cvt2(nf3.x, nf3.y, q1h.z, q2h.z, q3h.z); \
    cvt2(nf3.z, nf3.w, q1h.w, q2h.w, q3h.w); \
    *(uint4*)(bb_ +     0 + rowbyte_s + swz0) = q1l; \
    *(uint4*)(bb_ +     0 + rowbyte_s + swz1) = q1h; \
    *(uint4*)(bb_ +  8192 + rowbyte_s + swz0) = q2l; \
    *(uint4*)(bb_ +  8192 + rowbyte_s + swz1) = q2h; \
    *(uint4*)(bb_ + 16384 + rowbyte_s + swz0) = q3l; \
    *(uint4*)(bb_ + 16384 + rowbyte_s + swz1) = q3h; \
    cvt2(ng0.x, ng0.y, q1l.x, q2l.x, q3l.x); \
    cvt2(ng0.z, ng0.w, q1l.y, q2l.y, q3l.y); \
    cvt2(ng1.x, ng1.y, q1l.z, q2l.z, q3l.z); \
    cvt2(ng1.z, ng1.w, q1l.w, q2l.w, q3l.w); \
    cvt2(ng2.x, ng2.y, q1h.x, q2h.x, q3h.x); \
    cvt2(ng2.z, ng2.w, q1h.y, q2h.y, q3h.y); \
    cvt2(ng3.x, ng3.y, q1h.z, q2h.z, q3h.z); \
    cvt2(ng3.z, ng3.w, q1h.w, q2h.w, q3h.w); \
    *(uint4*)(bb_ + 24576 + rowbyte_s + swz0) = q1l; \
    *(uint4*)(bb_ + 24576 + rowbyte_s + swz1) = q1h; \
    *(uint4*)(bb_ + 32768 + rowbyte_s + swz0) = q2l; \
    *(uint4*)(bb_ + 32768 + rowbyte_s + swz1) = q2h; \
    *(uint4*)(bb_ + 40960 + rowbyte_s + swz0) = q3l; \
    *(uint4*)(bb_ + 40960 + rowbyte_s + swz1) = q3h; \
  } while (0)

#define MFMA(a, b, c) __builtin_amdgcn_mfma_f32_32x32x16_bf16((a), (b), (c), 0, 0, 0)

#define COMPUTE() do { \
    const unsigned char* bb_ = smem; \
    _Pragma("unroll") \
    for (int s = 0; s < 4; ++s) { \
      const int off_ = ((2 * s + h2) ^ r7) << 4; \
      const short8v a1_ = *(const short8v*)(bb_ +     0 + byteA + off_); \
      const short8v b1_ = *(const short8v*)(bb_ + 24576 + byteB + off_); \
      if (s < 2) acc_m0 = MFMA(a1_, b1_, acc_m0); \
      else       acc_m1 = MFMA(a1_, b1_, acc_m1); \
      const short8v a2_ = *(const short8v*)(bb_ +  8192 + byteA + off_); \
      const short8v b2_ = *(const short8v*)(bb_ + 32768 + byteB + off_); \
      acc_c = MFMA(a1_, b2_, acc_c); \
      acc_c = MFMA(a2_, b1_, acc_c); \
      const short8v a3_ = *(const short8v*)(bb_ + 16384 + byteA + off_); \
      const short8v b3_ = *(const short8v*)(bb_ + 40960 + byteB + off_); \
      acc_c = MFMA(a1_, b3_, acc_c); \
      acc_c = MFMA(a2_, b2_, acc_c); \
      acc_c = MFMA(a3_, b1_, acc_c); \
    } \
  } while (0)

  // ---- K-loop over this block's slice: gload(c+1) | compute(c) | bar | swrite | bar
  GLOAD(cStart);
  SWRITE();
  __syncthreads();
  for (int c = cStart; c < cEnd; ++c) {
    const bool more = (c + 1 < cEnd);
    if (more) GLOAD(c + 1);
    COMPUTE();
    __syncthreads();
    if (more) { SWRITE(); __syncthreads(); }
  }

  if (ks == 1) {
    // epilogue in-kernel: fin aliases staging (all reads drained by barrier)
    float* fin = (float*)smem;
#pragma unroll
    for (int reg = 0; reg < 16; ++reg) {
      const int rowf = (reg & 3) + 8 * (reg >> 2) + 4 * h2;
      fin[(wm * 32 + rowf) * 64 + we * 32 + r] = (acc_m0[reg] + acc_m1[reg]) + acc_c[reg];
    }
    __syncthreads();
    topk_softmax(fin, bias, out, tokBase, lane, wv);
  } else {
    // write partial logits [kt][tile][64][64] to workspace
    float* pp = part + ((size_t)kt * (TOKS / BM) + blockIdx.x) * 4096;
#pragma unroll
    for (int reg = 0; reg < 16; ++reg) {
      const int rowf = (reg & 3) + 8 * (reg >> 2) + 4 * h2;
      pp[(wm * 32 + rowf) * 64 + we * 32 + r] = (acc_m0[reg] + acc_m1[reg]) + acc_c[reg];
    }
  }
}

// ---- stage 2: sum ks partial planes + topk. 256 blocks x 256 thr ----
__global__ __launch_bounds__(256)
void reduce_topk_kernel(const float* __restrict__ part,
                        const float* __restrict__ bias,
                        float* __restrict__ out, int ks) {
  __shared__ __align__(16) float fin[4096];
  const int tid  = threadIdx.x;
  const int lane = tid & 63;
  const int wv   = tid >> 6;
  const int tokBase = blockIdx.x * BM;

  const float* p0 = part + (size_t)blockIdx.x * 4096 + tid * 16;
  float4 s0 = *(const float4*)(p0);
  float4 s1 = *(const float4*)(p0 + 4);
  float4 s2 = *(const float4*)(p0 + 8);
  float4 s3 = *(const float4*)(p0 + 12);
  for (int kt = 1; kt < ks; ++kt) {
    const float* p = p0 + (size_t)kt * ((TOKS / BM) * 4096);
    const float4 q0 = *(const float4*)(p);
    const float4 q1 = *(const float4*)(p + 4);
    const float4 q2 = *(const float4*)(p + 8);
    const float4 q3 = *(const float4*)(p + 12);
    s0.x += q0.x; s0.y += q0.y; s0.z += q0.z; s0.w += q0.w;
    s1.x += q1.x; s1.y += q1.y; s1.z += q1.z; s1.w += q1.w;
    s2.x += q2.x; s2.y += q2.y; s2.z += q2.z; s2.w += q2.w;
    s3.x += q3.x; s3.y += q3.y; s3.z += q3.z; s3.w += q3.w;
  }
  *(float4*)(&fin[tid * 16])      = s0;
  *(float4*)(&fin[tid * 16 + 4])  = s1;
  *(float4*)(&fin[tid * 16 + 8])  = s2;
  *(float4*)(&fin[tid * 16 + 12]) = s3;
  __syncthreads();
  topk_softmax(fin, bias, out, tokBase, lane, wv);
}

extern "C" void kernel_launch(void* const* d_in, const int* in_sizes, int n_in,
                              void* d_out, int out_size, void* d_ws, size_t ws_size,
                              hipStream_t stream) {
  const float* x    = (const float*)d_in[0];
  const float* wgt  = (const float*)d_in[1];
  const float* bias = (const float*)d_in[2];
  float* out  = (float*)d_out;
  float* part = (float*)d_ws;

  const size_t planeBytes = (size_t)(TOKS / BM) * 4096 * sizeof(float);  // 4 MiB
  const int ks = (ws_size >= 3 * planeBytes) ? 3 : (ws_size >= 2 * planeBytes ? 2 : 1);

  hipLaunchKernelGGL(router_mfma_kernel, dim3(TOKS / BM, ks), dim3(256), 0, stream,
                     x, wgt, bias, out, part, ks);
  if (ks > 1) {
    hipLaunchKernelGGL(reduce_topk_kernel, dim3(TOKS / BM), dim3(256), 0, stream,
                       part, bias, out, ks);
  }
}